// Round 2
// 420.455 us; speedup vs baseline: 1.0108x; 1.0108x over previous
//
#include <hip/hip_runtime.h>

// Row-wise L1 normalization: x[bs, r, d] -> x * 1/max(rowsum, EPS)
// bs=16, r=2048, d=2048, fp32.
//
// One 64-lane WAVE per row (4 rows per 256-thread block):
//  - each lane holds 8 float4 (32 floats) in registers -> 8 loads in
//    flight per lane, input read from HBM exactly once
//  - reduction is a pure-register __shfl_xor butterfly: no LDS, no
//    __syncthreads, no thread-0 serialization (every lane gets the sum)
//  - nontemporal load/store hints: 512 MB stream has zero reuse, keep it
//    out of L2
//
// Note: use a native clang vector type (ext_vector_type) — HIP's float4 is
// a class and __builtin_nontemporal_* rejects it.

typedef float f32x4 __attribute__((ext_vector_type(4)));

#define ROW_LEN 2048
#define BLOCK   256
#define WAVES_PER_BLOCK (BLOCK / 64)       // 4 rows per block
#define V4_PER_LANE     (ROW_LEN / 4 / 64) // 8 float4 per lane

__global__ __launch_bounds__(BLOCK) void rownorm_kernel(
    const float* __restrict__ in, float* __restrict__ out) {
    const int lane = threadIdx.x & 63;
    const int wid  = threadIdx.x >> 6;
    const int row  = blockIdx.x * WAVES_PER_BLOCK + wid;
    const size_t base = (size_t)row * ROW_LEN;
    const f32x4* __restrict__ in4 = (const f32x4*)(in + base);
    f32x4* __restrict__ out4      = (f32x4*)(out + base);

    // 8 independent coalesced 1 KiB wave-loads, all issued before any use.
    f32x4 v[V4_PER_LANE];
    #pragma unroll
    for (int k = 0; k < V4_PER_LANE; ++k)
        v[k] = __builtin_nontemporal_load(&in4[lane + 64 * k]);

    float s = 0.0f;
    #pragma unroll
    for (int k = 0; k < V4_PER_LANE; ++k)
        s += (v[k].x + v[k].y) + (v[k].z + v[k].w);

    // 64-lane butterfly: every lane ends up with the full row sum.
    #pragma unroll
    for (int off = 1; off < 64; off <<= 1)
        s += __shfl_xor(s, off, 64);

    const float inv = 1.0f / fmaxf(s, 1e-5f);

    #pragma unroll
    for (int k = 0; k < V4_PER_LANE; ++k) {
        f32x4 o = v[k] * inv;
        __builtin_nontemporal_store(o, &out4[lane + 64 * k]);
    }
}

extern "C" void kernel_launch(void* const* d_in, const int* in_sizes, int n_in,
                              void* d_out, int out_size, void* d_ws, size_t ws_size,
                              hipStream_t stream) {
    const float* in = (const float*)d_in[0];
    float* out = (float*)d_out;
    const int n_rows = in_sizes[0] / ROW_LEN;           // 16 * 2048 = 32768
    const int n_blocks = n_rows / WAVES_PER_BLOCK;      // 8192
    rownorm_kernel<<<n_blocks, BLOCK, 0, stream>>>(in, out);
}